// Round 11
// baseline (211.691 us; speedup 1.0000x reference)
//
#include <hip/hip_runtime.h>
#include <stdint.h>

typedef unsigned short u16;
typedef __attribute__((ext_vector_type(8))) short short8;
typedef __attribute__((ext_vector_type(4))) float floatx4;

constexpr int B_ = 64, P_ = 2000, D_ = 128, T_ = 200;

__device__ __forceinline__ u16 f2bf(float f) {
  union { float f; uint32_t u; } v; v.f = f;
  return (u16)((v.u + 0x7fffu + ((v.u >> 16) & 1u)) >> 16);
}

// async global->LDS, 16B per lane (global_load_lds_dwordx4). Dest must be
// wave-uniform-base + lane*16 (m104); our staging is tid-linear so this holds.
__device__ __forceinline__ void g2lds16(const void* g, void* l) {
  __builtin_amdgcn_global_load_lds(
      (const __attribute__((address_space(1))) uint32_t*)g,
      (__attribute__((address_space(3))) uint32_t*)l, 16, 0, 0);
}

// ---- fused prologue: blocks 0..63 counting-sort customer ids by tour (per batch);
// blocks 64..127 zero ssum||ssq (ws poisoned 0xAA); blocks 128..151 pack fp32
// W1 (256x128) / W2 (128x128) into bf16 MFMA B-fragment order.
// frag id = (ks*8 + nt)*64 + lane ; lane holds B[k0+j][nt*16 + (lane&15)], j=0..7,
// k0 = ks*32 + (lane>>4)*8.  W1: 8 ksteps (4096 frags). W2: 4 ksteps (2048 frags).
// NOTE: each kstep is a contiguous 8 KB block (frag-linear) -> stageable by
// global_load_lds with tid-linear addressing.
__global__ __launch_bounds__(256) void k_pre(
    const int* __restrict__ tidx, int* __restrict__ list,
    int* __restrict__ goff, int* __restrict__ gcnt,
    const float* __restrict__ W1, const float* __restrict__ W2,
    u16* __restrict__ w1f, u16* __restrict__ w2f, float* __restrict__ ssum) {
  __shared__ int tix[P_];
  __shared__ int cnt[256], scan[256], cur[256];
  const int bid = blockIdx.x, tid = threadIdx.x;

  if (bid >= 64) {
    if (bid < 128) {            // 64*256 = 16384 = 2*B_*D_ exactly
      ssum[(bid - 64) * 256 + tid] = 0.f;
      return;
    }
    int t = (bid - 128) * 256 + tid;   // 24 blocks * 256 = 6144 exactly
    if (t >= 6144) return;
    const float* W = (t < 4096) ? W1 : W2;
    u16* dst = (t < 4096) ? w1f : w2f;
    int fid = (t < 4096) ? t : t - 4096;
    int lane = fid & 63;
    int nt = (fid >> 6) & 7;
    int ks = fid >> 9;
    int quad = lane >> 4, c = lane & 15;
    int k0 = ks * 32 + quad * 8;
#pragma unroll
    for (int j = 0; j < 8; ++j)
      dst[(size_t)fid * 8 + j] = f2bf(W[(k0 + j) * D_ + nt * 16 + c]);
    return;
  }

  // ---- counting sort (one block per batch b = bid). INT LDS atomics only. ----
  const int b = bid;
  cnt[tid] = 0;
  for (int i = tid; i < P_; i += 256) tix[i] = tidx[b * P_ + i];
  __syncthreads();
  for (int i = tid; i < P_; i += 256) atomicAdd(&cnt[tix[i]], 1);
  __syncthreads();
  scan[tid] = cnt[tid];
  __syncthreads();
  for (int s = 1; s < 256; s <<= 1) {
    int v = (tid >= s) ? scan[tid - s] : 0;
    __syncthreads();
    scan[tid] += v;
    __syncthreads();
  }
  int excl = scan[tid] - cnt[tid];
  if (tid < T_) {
    goff[b * T_ + tid] = excl;
    gcnt[b * T_ + tid] = cnt[tid];
  }
  cur[tid] = excl;
  __syncthreads();
  for (int i = tid; i < P_; i += 256) {
    int slot = atomicAdd(&cur[tix[i]], 1);
    list[b * P_ + slot] = i;
  }
}

// ---- gather: one wave per (b,t) segment; register-sum its rows; bf16 write ----
// grid 3200 x 256 thr (4 waves): seg = blockIdx*4 + wave, 12,800 segments exact.
__global__ __launch_bounds__(256) void k_gather(const float* __restrict__ emb,
                                                const int* __restrict__ list,
                                                const int* __restrict__ goff,
                                                const int* __restrict__ gcnt,
                                                u16* __restrict__ tourb) {
  const int tid = threadIdx.x;
  const int lane = tid & 63, wv = tid >> 6;
  const int seg = blockIdx.x * 4 + wv;          // = b*T_ + t
  const int b = seg / T_;
  const int off = goff[seg], cn = gcnt[seg];
  const int* lstb = list + b * P_;
  const float* eb = emb + ((size_t)(b * 2001 + 1)) * D_ + lane * 2;
  float sx = 0.f, sy = 0.f;
  for (int i = 0; i < cn; i += 8) {
    int pr[8];
#pragma unroll
    for (int j = 0; j < 8; ++j)
      if (i + j < cn) pr[j] = lstb[off + i + j];
    float2 v[8];
#pragma unroll
    for (int j = 0; j < 8; ++j)
      if (i + j < cn) v[j] = *(const float2*)(eb + (size_t)pr[j] * D_);
#pragma unroll
    for (int j = 0; j < 8; ++j)
      if (i + j < cn) { sx += v[j].x; sy += v[j].y; }
  }
  uint32_t pk = (uint32_t)f2bf(sx) | ((uint32_t)f2bf(sy) << 16);
  ((uint32_t*)(tourb + (size_t)seg * D_))[lane] = pk;
}

// ---- fused MLP + stats: h = relu(x@W1+b1); h = h@W2+b2; out = cust + h;
// per-(b,col) sum / sumsq accumulated in-kernel.
// R6: global_load_lds double-buffered weight staging (8 KB/kstep) — 78->68.5us,
// clean traffic (55/68 MB), but 15 full-drain barriers/block with only 4
// MFMAs/kstep/wave against each drain.
// R8: amortize — 64 rows/block (2000 blocks), 4 waves x 16 rows x 128 cols
// (R2's proven wave shape). Same staging schedule; block-generations/CU halve,
// MFMA work per barrier doubles. eemb hoist moved after GEMM1 (xa/ta dead).
// R9/R10: resubmitted unchanged (R8/R9 benches never ran: GPU acquisition timeout).
__global__ __launch_bounds__(256, 4) void k_mlp(
    const int* __restrict__ tidx, const float* __restrict__ emb,
    const u16* __restrict__ tourb,
    const u16* __restrict__ w1f, const u16* __restrict__ w2f,
    const float* __restrict__ b1, const float* __restrict__ b2,
    float* __restrict__ ssum, float* __restrict__ ssq,
    float* __restrict__ out) {
  __shared__ u16 wbuf[2][4096];    // 2 x 8 KB weight double-buffer (one kstep each)
  __shared__ u16 hbuf[64 * 136];   // stride 136: 16B-aligned rows, 2-way banks (free)
  __shared__ float red[2][2][128]; // [b-slot][sum|sq][col], 2 KB
  const int tid = threadIdx.x;
  const int w = tid >> 6, lane = tid & 63, quad = lane >> 4, c = lane & 15;
  const int base = blockIdx.x * 64;
  const int r0 = w * 16;           // wave's 16-row tile within the block

  // zero stats reduction buffer (ordered before epilogue-2 by the mid barriers)
  for (int i = tid; i < 512; i += 256) ((float*)red)[i] = 0.f;

  const int blo = base / P_;
  const int bhi = (base + 63) / P_;
  const bool straddle = (blo != bhi);
  const int bsplit = bhi * P_;

  const int m0 = base + r0 + c;              // this lane's A-row (global row id)
  const int ab = m0 / P_, ap = m0 - ab * P_;
  const float* arow = emb + ((size_t)(ab * 2001 + 1 + ap)) * D_;
  const u16* trow = tourb + ((size_t)(ab * T_ + tidx[m0])) * D_;

  // stage W1 kstep 0 into wbuf[0]: 8 KB = 256 thr x 2 x 16 B, tid-linear.
  g2lds16(w1f + (size_t)tid * 8,        (u16*)wbuf[0] + (size_t)tid * 8);
  g2lds16(w1f + 2048 + (size_t)tid * 8, (u16*)wbuf[0] + 2048 + (size_t)tid * 8);

  // hoist ALL A inputs: 4 fp32 ksteps (32 regs) + 4 bf16 tour ksteps (16 regs).
  floatx4 xa[4][2];
#pragma unroll
  for (int ks = 0; ks < 4; ++ks) {
    const float* src = arow + ks * 32 + quad * 8;
    xa[ks][0] = *(const floatx4*)src;
    xa[ks][1] = *(const floatx4*)(src + 4);
  }
  short8 ta[4];
#pragma unroll
  for (int ks = 0; ks < 4; ++ks)
    ta[ks] = *(const short8*)(trow + ks * 32 + quad * 8);

  float bias1[8], bias2[8];
#pragma unroll
  for (int nt = 0; nt < 8; ++nt) {
    bias1[nt] = b1[nt * 16 + c];
    bias2[nt] = b2[nt * 16 + c];
  }

  floatx4 acc[8];
#pragma unroll
  for (int nt = 0; nt < 8; ++nt) acc[nt] = (floatx4)0.f;

  __syncthreads();   // wbuf[0] staged (vmcnt drain) + red zero ordered

  // ---- GEMM1: K=256, 8 ksteps. Per iter: stage next kstep -> compute cur ->
  // barrier (HIP __syncthreads drains vmcnt -> staged buf ready, race-free). ----
#pragma unroll
  for (int ks = 0; ks < 8; ++ks) {
    const int cur = ks & 1;
    if (ks < 7) {   // stage W1 kstep ks+1
      const u16* src = w1f + (size_t)(ks + 1) * 4096;
      g2lds16(src + (size_t)tid * 8,        (u16*)wbuf[cur ^ 1] + (size_t)tid * 8);
      g2lds16(src + 2048 + (size_t)tid * 8, (u16*)wbuf[cur ^ 1] + 2048 + (size_t)tid * 8);
    } else {        // stage W2 kstep 0 into wbuf[0] (its readers done at ks=6 barrier)
      g2lds16(w2f + (size_t)tid * 8,        (u16*)wbuf[0] + (size_t)tid * 8);
      g2lds16(w2f + 2048 + (size_t)tid * 8, (u16*)wbuf[0] + 2048 + (size_t)tid * 8);
    }
    short8 a;
    if (ks < 4) {
#pragma unroll
      for (int j = 0; j < 4; ++j) {
        a[j]     = (short)f2bf(xa[ks][0][j]);
        a[4 + j] = (short)f2bf(xa[ks][1][j]);
      }
    } else {
      a = ta[ks - 4];
    }
#pragma unroll
    for (int nt = 0; nt < 8; ++nt) {
      short8 bf = *(const short8*)(&wbuf[cur][(nt * 64 + lane) * 8]);
      acc[nt] = __builtin_amdgcn_mfma_f32_16x16x32_bf16(a, bf, acc[nt], 0, 0, 0);
    }
    if (ks == 7) {
      // epilogue 1 before the barrier: relu(acc+b1) -> hbuf bf16
#pragma unroll
      for (int nt = 0; nt < 8; ++nt)
#pragma unroll
        for (int r = 0; r < 4; ++r) {
          int row = r0 + quad * 4 + r;
          float v = acc[nt][r] + bias1[nt];
          hbuf[row * 136 + nt * 16 + c] = f2bf(v > 0.f ? v : 0.f);
        }
    }
    __syncthreads();
  }

  // hoist epilogue-2 emb loads (xa/ta dead now): in flight across GEMM2.
  float eemb[8][4];
#pragma unroll
  for (int nt = 0; nt < 8; ++nt)
#pragma unroll
    for (int r = 0; r < 4; ++r) {
      int m = base + r0 + quad * 4 + r;
      int b = m / P_, p = m - b * P_;
      eemb[nt][r] = emb[((size_t)(b * 2001 + 1 + p)) * D_ + nt * 16 + c];
    }

  // ---- GEMM2: K=128, 4 ksteps; A-frags from hbuf, weights staged same way ----
  floatx4 acc2[8];
#pragma unroll
  for (int nt = 0; nt < 8; ++nt) acc2[nt] = (floatx4)0.f;

#pragma unroll
  for (int ks = 0; ks < 4; ++ks) {
    const int cur = ks & 1;
    if (ks < 3) {   // stage W2 kstep ks+1
      const u16* src = w2f + (size_t)(ks + 1) * 4096;
      g2lds16(src + (size_t)tid * 8,        (u16*)wbuf[cur ^ 1] + (size_t)tid * 8);
      g2lds16(src + 2048 + (size_t)tid * 8, (u16*)wbuf[cur ^ 1] + 2048 + (size_t)tid * 8);
    }
    short8 a = *(const short8*)(&hbuf[(r0 + c) * 136 + ks * 32 + quad * 8]);
#pragma unroll
    for (int nt = 0; nt < 8; ++nt) {
      short8 bf = *(const short8*)(&wbuf[cur][(nt * 64 + lane) * 8]);
      acc2[nt] = __builtin_amdgcn_mfma_f32_16x16x32_bf16(a, bf, acc2[nt], 0, 0, 0);
    }
    if (ks < 3) __syncthreads();
  }

  // epilogue 2: out = cust + (acc2 + b2), fused per-column stats.
  float s[8], q[8];
#pragma unroll
  for (int nt = 0; nt < 8; ++nt) { s[nt] = 0.f; q[nt] = 0.f; }
#pragma unroll
  for (int nt = 0; nt < 8; ++nt)
#pragma unroll
    for (int r = 0; r < 4; ++r) {
      int row = r0 + quad * 4 + r;
      int m = base + row;
      int b = m / P_, p = m - b * P_;
      size_t gaddr = ((size_t)(b * 2001 + 1 + p)) * D_ + nt * 16 + c;
      float v = eemb[nt][r] + (acc2[nt][r] + bias2[nt]);
      out[gaddr] = v;
      if (!straddle || m < bsplit) {
        s[nt] += v; q[nt] += v * v;
      } else {  // rare: block straddles a batch boundary (~32/2000 blocks)
        atomicAdd(&red[1][0][nt * 16 + c], v);
        atomicAdd(&red[1][1][nt * 16 + c], v * v);
      }
    }
  // fold the quad dimension in-register first (lanes ^16/^32 share (nt,c)):
#pragma unroll
  for (int nt = 0; nt < 8; ++nt) {
    s[nt] += __shfl_xor(s[nt], 16);
    s[nt] += __shfl_xor(s[nt], 32);
    q[nt] += __shfl_xor(q[nt], 16);
    q[nt] += __shfl_xor(q[nt], 32);
  }
  if (quad == 0) {
#pragma unroll
    for (int nt = 0; nt < 8; ++nt) {
      atomicAdd(&red[0][0][nt * 16 + c], s[nt]);
      atomicAdd(&red[0][1][nt * 16 + c], q[nt]);
    }
  }
  __syncthreads();
  if (tid < 128) {
    atomicAdd(&ssum[blo * D_ + tid], red[0][0][tid]);
    if (straddle) atomicAdd(&ssum[bhi * D_ + tid], red[1][0][tid]);
  } else {
    int col = tid - 128;
    atomicAdd(&ssq[blo * D_ + col], red[0][1][col]);
    if (straddle) atomicAdd(&ssq[bhi * D_ + col], red[1][1][col]);
  }
}

// ---- in-place normalize (rstd/scale recomputed from ssum/ssq per thread)
// + depot-row copy. 8004 blocks * 256 thr * 8 elems exact.
__global__ __launch_bounds__(256) void k_out(
    const float* __restrict__ emb,
    const float* __restrict__ ssum, const float* __restrict__ ssq,
    const float* __restrict__ gamma, const float* __restrict__ beta,
    float* __restrict__ out) {
  size_t i = ((size_t)blockIdx.x * 256 + threadIdx.x) * 8;
  int row = (int)(i >> 7), col = (int)(i & 127);
  int b = row / 2001, r = row - b * 2001;
  if (r == 0) {
    *(floatx4*)(out + i)     = *(const floatx4*)(emb + i);
    *(floatx4*)(out + i + 4) = *(const floatx4*)(emb + i + 4);
  } else {
    floatx4 a0 = *(const floatx4*)(out + i);
    floatx4 a1 = *(const floatx4*)(out + i + 4);
    int cc = b * D_ + col;
    floatx4 su0 = *(const floatx4*)(ssum + cc);
    floatx4 su1 = *(const floatx4*)(ssum + cc + 4);
    floatx4 sq0 = *(const floatx4*)(ssq + cc);
    floatx4 sq1 = *(const floatx4*)(ssq + cc + 4);
    floatx4 g0  = *(const floatx4*)(gamma + col);
    floatx4 g1  = *(const floatx4*)(gamma + col + 4);
    floatx4 be0 = *(const floatx4*)(beta + col);
    floatx4 be1 = *(const floatx4*)(beta + col + 4);
    constexpr float invP = 1.f / P_;
#pragma unroll
    for (int j = 0; j < 4; ++j) {
      float mean = su0[j] * invP;
      float var  = sq0[j] * invP - mean * mean;
      float sc   = rsqrtf(var + 1e-5f) * g0[j];
      a0[j] = a0[j] * sc + (be0[j] - mean * sc);
      float mean1 = su1[j] * invP;
      float var1  = sq1[j] * invP - mean1 * mean1;
      float sc1   = rsqrtf(var1 + 1e-5f) * g1[j];
      a1[j] = a1[j] * sc1 + (be1[j] - mean1 * sc1);
    }
    *(floatx4*)(out + i)     = a0;
    *(floatx4*)(out + i + 4) = a1;
  }
}

extern "C" void kernel_launch(void* const* d_in, const int* in_sizes, int n_in,
                              void* d_out, int out_size, void* d_ws, size_t ws_size,
                              hipStream_t stream) {
  // inputs: 0 batch_size(i32), 1 num_customers(i32), 2 tour_index(i32),
  // 3 embeddings(f32), 4 W1(f32), 5 b1(f32), 6 W2(f32), 7 b2(f32),
  // 8 gamma(f32), 9 beta(f32)
  const int*   tour_index = (const int*)d_in[2];
  const float* emb   = (const float*)d_in[3];
  const float* W1    = (const float*)d_in[4];
  const float* b1    = (const float*)d_in[5];
  const float* W2    = (const float*)d_in[6];
  const float* b2    = (const float*)d_in[7];
  const float* gamma = (const float*)d_in[8];
  const float* beta  = (const float*)d_in[9];
  float* out = (float*)d_out;
  char* ws = (char*)d_ws;

  // ws layout (~4.2 MB):
  u16*   w1f   = (u16*)(ws);                 //    65,536 B
  u16*   w2f   = (u16*)(ws + 65536);         //    32,768 B
  float* ssum  = (float*)(ws + 98304);       //    65,536 B (ssum || ssq)
  float* ssq   = ssum + B_ * D_;
  u16*   tourb = (u16*)(ws + 229376);        // 3,276,800 B (bf16 tour table)
  int*   list  = (int*)(ws + 3506176);       //   512,000 B (sorted customer ids)
  int*   goff  = (int*)(ws + 4018176);       //    51,200 B
  int*   gcnt  = (int*)(ws + 4069376);       //    51,200 B

  hipLaunchKernelGGL(k_pre,    dim3(152),  dim3(256), 0, stream,
                     tour_index, list, goff, gcnt, W1, W2, w1f, w2f, ssum);
  hipLaunchKernelGGL(k_gather, dim3(3200), dim3(256), 0, stream, emb, list, goff, gcnt, tourb);
  hipLaunchKernelGGL(k_mlp,    dim3(2000), dim3(256), 0, stream, tour_index, emb, tourb,
                     w1f, w2f, b1, b2, ssum, ssq, out);
  hipLaunchKernelGGL(k_out,    dim3(8004), dim3(256), 0, stream, emb, ssum, ssq, gamma, beta, out);
}

// Round 12
// 210.113 us; speedup vs baseline: 1.0075x; 1.0075x over previous
//
#include <hip/hip_runtime.h>
#include <stdint.h>

typedef unsigned short u16;
typedef __attribute__((ext_vector_type(8))) short short8;
typedef __attribute__((ext_vector_type(4))) float floatx4;

constexpr int B_ = 64, P_ = 2000, D_ = 128, T_ = 200;

__device__ __forceinline__ u16 f2bf(float f) {
  union { float f; uint32_t u; } v; v.f = f;
  return (u16)((v.u + 0x7fffu + ((v.u >> 16) & 1u)) >> 16);
}

// async global->LDS, 16B per lane (global_load_lds_dwordx4). Dest must be
// wave-uniform-base + lane*16 (m104); our staging is tid-linear so this holds.
__device__ __forceinline__ void g2lds16(const void* g, void* l) {
  __builtin_amdgcn_global_load_lds(
      (const __attribute__((address_space(1))) uint32_t*)g,
      (__attribute__((address_space(3))) uint32_t*)l, 16, 0, 0);
}

// ---- fused prologue: blocks 0..63 counting-sort customer ids by tour (per batch);
// blocks 64..127 zero ssum||ssq (ws poisoned 0xAA); blocks 128..151 pack fp32
// W1 (256x128) / W2 (128x128) into bf16 MFMA B-fragment order.
// frag id = (ks*8 + nt)*64 + lane ; lane holds B[k0+j][nt*16 + (lane&15)], j=0..7,
// k0 = ks*32 + (lane>>4)*8.  W1: 8 ksteps (4096 frags). W2: 4 ksteps (2048 frags).
__global__ __launch_bounds__(256) void k_pre(
    const int* __restrict__ tidx, int* __restrict__ list,
    int* __restrict__ goff, int* __restrict__ gcnt,
    const float* __restrict__ W1, const float* __restrict__ W2,
    u16* __restrict__ w1f, u16* __restrict__ w2f, float* __restrict__ ssum) {
  __shared__ int tix[P_];
  __shared__ int cnt[256], scan[256], cur[256];
  const int bid = blockIdx.x, tid = threadIdx.x;

  if (bid >= 64) {
    if (bid < 128) {            // 64*256 = 16384 = 2*B_*D_ exactly
      ssum[(bid - 64) * 256 + tid] = 0.f;
      return;
    }
    int t = (bid - 128) * 256 + tid;   // 24 blocks * 256 = 6144 exactly
    if (t >= 6144) return;
    const float* W = (t < 4096) ? W1 : W2;
    u16* dst = (t < 4096) ? w1f : w2f;
    int fid = (t < 4096) ? t : t - 4096;
    int lane = fid & 63;
    int nt = (fid >> 6) & 7;
    int ks = fid >> 9;
    int quad = lane >> 4, c = lane & 15;
    int k0 = ks * 32 + quad * 8;
#pragma unroll
    for (int j = 0; j < 8; ++j)
      dst[(size_t)fid * 8 + j] = f2bf(W[(k0 + j) * D_ + nt * 16 + c]);
    return;
  }

  // ---- counting sort (one block per batch b = bid). INT LDS atomics only. ----
  const int b = bid;
  cnt[tid] = 0;
  for (int i = tid; i < P_; i += 256) tix[i] = tidx[b * P_ + i];
  __syncthreads();
  for (int i = tid; i < P_; i += 256) atomicAdd(&cnt[tix[i]], 1);
  __syncthreads();
  scan[tid] = cnt[tid];
  __syncthreads();
  for (int s = 1; s < 256; s <<= 1) {
    int v = (tid >= s) ? scan[tid - s] : 0;
    __syncthreads();
    scan[tid] += v;
    __syncthreads();
  }
  int excl = scan[tid] - cnt[tid];
  if (tid < T_) {
    goff[b * T_ + tid] = excl;
    gcnt[b * T_ + tid] = cnt[tid];
  }
  cur[tid] = excl;
  __syncthreads();
  for (int i = tid; i < P_; i += 256) {
    int slot = atomicAdd(&cur[tix[i]], 1);
    list[b * P_ + slot] = i;
  }
}

// ---- gather: one wave per (b,t) segment; register-sum its rows; bf16 write ----
// grid 3200 x 256 thr (4 waves): seg = blockIdx*4 + wave, 12,800 segments exact.
__global__ __launch_bounds__(256) void k_gather(const float* __restrict__ emb,
                                                const int* __restrict__ list,
                                                const int* __restrict__ goff,
                                                const int* __restrict__ gcnt,
                                                u16* __restrict__ tourb) {
  const int tid = threadIdx.x;
  const int lane = tid & 63, wv = tid >> 6;
  const int seg = blockIdx.x * 4 + wv;          // = b*T_ + t
  const int b = seg / T_;
  const int off = goff[seg], cn = gcnt[seg];
  const int* lstb = list + b * P_;
  const float* eb = emb + ((size_t)(b * 2001 + 1)) * D_ + lane * 2;
  float sx = 0.f, sy = 0.f;
  for (int i = 0; i < cn; i += 8) {
    int pr[8];
#pragma unroll
    for (int j = 0; j < 8; ++j)
      if (i + j < cn) pr[j] = lstb[off + i + j];
    float2 v[8];
#pragma unroll
    for (int j = 0; j < 8; ++j)
      if (i + j < cn) v[j] = *(const float2*)(eb + (size_t)pr[j] * D_);
#pragma unroll
    for (int j = 0; j < 8; ++j)
      if (i + j < cn) { sx += v[j].x; sy += v[j].y; }
  }
  uint32_t pk = (uint32_t)f2bf(sx) | ((uint32_t)f2bf(sy) << 16);
  ((uint32_t*)(tourb + (size_t)seg * D_))[lane] = pk;
}

// ---- fused MLP + stats: h = relu(x@W1+b1); h = h@W2+b2; out = cust + h;
// per-(b,col) sum / sumsq accumulated in-kernel.
// R6 (measured best, 68.5us): 32 rows/block, 4000 blocks, 2x2 wave grid,
// W1+W2 staged via global_load_lds double-buffer.
// R8 (64-row amortization): REGRESSED to 80us (occ 41->30%) — reverted.
// R11 delta on R6: GEMM2 weights via VMEM (W2 is 32KB, L2-hot) instead of
// staged — removes 3 in-loop barrier drains + the ks=7 W2 prefetch; GEMM2 +
// eemb hoist + epilogue become one barrier-free region the compiler can
// software-pipeline. Barriers/block 13 -> 10 (ks=7's is drain-free).
__global__ __launch_bounds__(256, 5) void k_mlp(
    const int* __restrict__ tidx, const float* __restrict__ emb,
    const u16* __restrict__ tourb,
    const u16* __restrict__ w1f, const u16* __restrict__ w2f,
    const float* __restrict__ b1, const float* __restrict__ b2,
    float* __restrict__ ssum, float* __restrict__ ssq,
    float* __restrict__ out) {
  __shared__ u16 wbuf[2][4096];    // 2 x 8 KB W1 double-buffer (one kstep each)
  __shared__ u16 hbuf[32 * 136];   // stride 136: 16B-aligned rows, 2-way banks (free)
  __shared__ float red[2][2][128]; // [b-slot][sum|sq][col], 2 KB
  const int tid = threadIdx.x;
  const int w = tid >> 6, lane = tid & 63, quad = lane >> 4, c = lane & 15;
  const int wr = w >> 1, wc = w & 1;   // wave's (row, col) position in 2x2 grid
  const int base = blockIdx.x * 32;
  const int r0 = wr * 16;              // wave's 16-row tile within the block

  // zero stats reduction buffer (ordered before epilogue-2 by the mid barriers)
  for (int i = tid; i < 512; i += 256) ((float*)red)[i] = 0.f;

  const int blo = base / P_;
  const int bhi = (base + 31) / P_;
  const bool straddle = (blo != bhi);
  const int bsplit = bhi * P_;

  const int m0 = base + r0 + c;              // this lane's A-row (global row id)
  const int ab = m0 / P_, ap = m0 - ab * P_;
  const float* arow = emb + ((size_t)(ab * 2001 + 1 + ap)) * D_;
  const u16* trow = tourb + ((size_t)(ab * T_ + tidx[m0])) * D_;

  // stage W1 kstep 0 into wbuf[0]: 8 KB = 256 thr x 2 x 16 B, tid-linear.
  g2lds16(w1f + (size_t)tid * 8,        (u16*)wbuf[0] + (size_t)tid * 8);
  g2lds16(w1f + 2048 + (size_t)tid * 8, (u16*)wbuf[0] + 2048 + (size_t)tid * 8);

  // hoist ALL A inputs: 4 fp32 ksteps (32 regs) + 4 bf16 tour ksteps (16 regs).
  floatx4 xa[4][2];
#pragma unroll
  for (int ks = 0; ks < 4; ++ks) {
    const float* src = arow + ks * 32 + quad * 8;
    xa[ks][0] = *(const floatx4*)src;
    xa[ks][1] = *(const floatx4*)(src + 4);
  }
  short8 ta[4];
#pragma unroll
  for (int ks = 0; ks < 4; ++ks)
    ta[ks] = *(const short8*)(trow + ks * 32 + quad * 8);

  float bias1[4], bias2[4];
#pragma unroll
  for (int ntl = 0; ntl < 4; ++ntl) {
    bias1[ntl] = b1[(wc * 4 + ntl) * 16 + c];
    bias2[ntl] = b2[(wc * 4 + ntl) * 16 + c];
  }

  floatx4 acc[4];
#pragma unroll
  for (int ntl = 0; ntl < 4; ++ntl) acc[ntl] = (floatx4)0.f;

  __syncthreads();   // wbuf[0] staged (vmcnt drain) + red zero ordered

  // ---- GEMM1: K=256, 8 ksteps. Per iter: stage next kstep -> compute cur ->
  // barrier (HIP __syncthreads drains vmcnt -> staged buf ready, race-free).
  // ks=7 stages nothing; its barrier only publishes hbuf (drain-free). ----
#pragma unroll
  for (int ks = 0; ks < 8; ++ks) {
    const int cur = ks & 1;
    if (ks < 7) {   // stage W1 kstep ks+1
      const u16* src = w1f + (size_t)(ks + 1) * 4096;
      g2lds16(src + (size_t)tid * 8,        (u16*)wbuf[cur ^ 1] + (size_t)tid * 8);
      g2lds16(src + 2048 + (size_t)tid * 8, (u16*)wbuf[cur ^ 1] + 2048 + (size_t)tid * 8);
    }
    short8 a;
    if (ks < 4) {
#pragma unroll
      for (int j = 0; j < 4; ++j) {
        a[j]     = (short)f2bf(xa[ks][0][j]);
        a[4 + j] = (short)f2bf(xa[ks][1][j]);
      }
    } else {
      a = ta[ks - 4];
    }
#pragma unroll
    for (int ntl = 0; ntl < 4; ++ntl) {
      short8 bf = *(const short8*)(&wbuf[cur][((wc * 4 + ntl) * 64 + lane) * 8]);
      acc[ntl] = __builtin_amdgcn_mfma_f32_16x16x32_bf16(a, bf, acc[ntl], 0, 0, 0);
    }
    if (ks == 7) {
      // epilogue 1 before the barrier: relu(acc+b1) -> hbuf bf16
#pragma unroll
      for (int ntl = 0; ntl < 4; ++ntl)
#pragma unroll
        for (int r = 0; r < 4; ++r) {
          int row = r0 + quad * 4 + r;
          float v = acc[ntl][r] + bias1[ntl];
          hbuf[row * 136 + wc * 64 + ntl * 16 + c] = f2bf(v > 0.f ? v : 0.f);
        }
    }
    __syncthreads();
  }

  // hoist epilogue-2 emb loads: in flight across GEMM2 (barrier-free region).
  float eemb[4][4];
#pragma unroll
  for (int ntl = 0; ntl < 4; ++ntl)
#pragma unroll
    for (int r = 0; r < 4; ++r) {
      int m = base + r0 + quad * 4 + r;
      int b = m / P_, p = m - b * P_;
      eemb[ntl][r] = emb[((size_t)(b * 2001 + 1 + p)) * D_ + wc * 64 + ntl * 16 + c];
    }

  // ---- GEMM2: K=128, 4 ksteps; A-frags from hbuf, W2 frags via VMEM (L2-hot).
  // No barriers: compiler free to pipeline loads across MFMAs. ----
  floatx4 acc2[4];
#pragma unroll
  for (int ntl = 0; ntl < 4; ++ntl) acc2[ntl] = (floatx4)0.f;

#pragma unroll
  for (int ks = 0; ks < 4; ++ks) {
    short8 a = *(const short8*)(&hbuf[(r0 + c) * 136 + ks * 32 + quad * 8]);
#pragma unroll
    for (int ntl = 0; ntl < 4; ++ntl) {
      int nt = wc * 4 + ntl;
      short8 bf = *(const short8*)(w2f + ((size_t)((ks * 8 + nt) * 64 + lane)) * 8);
      acc2[ntl] = __builtin_amdgcn_mfma_f32_16x16x32_bf16(a, bf, acc2[ntl], 0, 0, 0);
    }
  }

  // epilogue 2: out = cust + (acc2 + b2), fused per-column stats.
  float s[4], q[4];
#pragma unroll
  for (int ntl = 0; ntl < 4; ++ntl) { s[ntl] = 0.f; q[ntl] = 0.f; }
#pragma unroll
  for (int ntl = 0; ntl < 4; ++ntl)
#pragma unroll
    for (int r = 0; r < 4; ++r) {
      int row = r0 + quad * 4 + r;
      int m = base + row;
      int b = m / P_, p = m - b * P_;
      int col = wc * 64 + ntl * 16 + c;
      size_t gaddr = ((size_t)(b * 2001 + 1 + p)) * D_ + col;
      float v = eemb[ntl][r] + (acc2[ntl][r] + bias2[ntl]);
      out[gaddr] = v;
      if (!straddle || m < bsplit) {
        s[ntl] += v; q[ntl] += v * v;
      } else {  // rare: block straddles a batch boundary (~32/4000 blocks)
        atomicAdd(&red[1][0][col], v);
        atomicAdd(&red[1][1][col], v * v);
      }
    }
  // fold the quad dimension in-register first (lanes ^16/^32 share col):
#pragma unroll
  for (int ntl = 0; ntl < 4; ++ntl) {
    s[ntl] += __shfl_xor(s[ntl], 16);
    s[ntl] += __shfl_xor(s[ntl], 32);
    q[ntl] += __shfl_xor(q[ntl], 16);
    q[ntl] += __shfl_xor(q[ntl], 32);
  }
  if (quad == 0) {
#pragma unroll
    for (int ntl = 0; ntl < 4; ++ntl) {
      int col = wc * 64 + ntl * 16 + c;
      atomicAdd(&red[0][0][col], s[ntl]);
      atomicAdd(&red[0][1][col], q[ntl]);
    }
  }
  __syncthreads();
  if (tid < 128) {
    atomicAdd(&ssum[blo * D_ + tid], red[0][0][tid]);
    if (straddle) atomicAdd(&ssum[bhi * D_ + tid], red[1][0][tid]);
  } else {
    int col = tid - 128;
    atomicAdd(&ssq[blo * D_ + col], red[0][1][col]);
    if (straddle) atomicAdd(&ssq[bhi * D_ + col], red[1][1][col]);
  }
}

// ---- in-place normalize (rstd/scale recomputed from ssum/ssq per thread)
// + depot-row copy. 8004 blocks * 256 thr * 8 elems exact.
__global__ __launch_bounds__(256) void k_out(
    const float* __restrict__ emb,
    const float* __restrict__ ssum, const float* __restrict__ ssq,
    const float* __restrict__ gamma, const float* __restrict__ beta,
    float* __restrict__ out) {
  size_t i = ((size_t)blockIdx.x * 256 + threadIdx.x) * 8;
  int row = (int)(i >> 7), col = (int)(i & 127);
  int b = row / 2001, r = row - b * 2001;
  if (r == 0) {
    *(floatx4*)(out + i)     = *(const floatx4*)(emb + i);
    *(floatx4*)(out + i + 4) = *(const floatx4*)(emb + i + 4);
  } else {
    floatx4 a0 = *(const floatx4*)(out + i);
    floatx4 a1 = *(const floatx4*)(out + i + 4);
    int cc = b * D_ + col;
    floatx4 su0 = *(const floatx4*)(ssum + cc);
    floatx4 su1 = *(const floatx4*)(ssum + cc + 4);
    floatx4 sq0 = *(const floatx4*)(ssq + cc);
    floatx4 sq1 = *(const floatx4*)(ssq + cc + 4);
    floatx4 g0  = *(const floatx4*)(gamma + col);
    floatx4 g1  = *(const floatx4*)(gamma + col + 4);
    floatx4 be0 = *(const floatx4*)(beta + col);
    floatx4 be1 = *(const floatx4*)(beta + col + 4);
    constexpr float invP = 1.f / P_;
#pragma unroll
    for (int j = 0; j < 4; ++j) {
      float mean = su0[j] * invP;
      float var  = sq0[j] * invP - mean * mean;
      float sc   = rsqrtf(var + 1e-5f) * g0[j];
      a0[j] = a0[j] * sc + (be0[j] - mean * sc);
      float mean1 = su1[j] * invP;
      float var1  = sq1[j] * invP - mean1 * mean1;
      float sc1   = rsqrtf(var1 + 1e-5f) * g1[j];
      a1[j] = a1[j] * sc1 + (be1[j] - mean1 * sc1);
    }
    *(floatx4*)(out + i)     = a0;
    *(floatx4*)(out + i + 4) = a1;
  }
}

extern "C" void kernel_launch(void* const* d_in, const int* in_sizes, int n_in,
                              void* d_out, int out_size, void* d_ws, size_t ws_size,
                              hipStream_t stream) {
  // inputs: 0 batch_size(i32), 1 num_customers(i32), 2 tour_index(i32),
  // 3 embeddings(f32), 4 W1(f32), 5 b1(f32), 6 W2(f32), 7 b2(f32),
  // 8 gamma(f32), 9 beta(f32)
  const int*   tour_index = (const int*)d_in[2];
  const float* emb   = (const float*)d_in[3];
  const float* W1    = (const float*)d_in[4];
  const float* b1    = (const float*)d_in[5];
  const float* W2    = (const float*)d_in[6];
  const float* b2    = (const float*)d_in[7];
  const float* gamma = (const float*)d_in[8];
  const float* beta  = (const float*)d_in[9];
  float* out = (float*)d_out;
  char* ws = (char*)d_ws;

  // ws layout (~4.2 MB):
  u16*   w1f   = (u16*)(ws);                 //    65,536 B
  u16*   w2f   = (u16*)(ws + 65536);         //    32,768 B
  float* ssum  = (float*)(ws + 98304);       //    65,536 B (ssum || ssq)
  float* ssq   = ssum + B_ * D_;
  u16*   tourb = (u16*)(ws + 229376);        // 3,276,800 B (bf16 tour table)
  int*   list  = (int*)(ws + 3506176);       //   512,000 B (sorted customer ids)
  int*   goff  = (int*)(ws + 4018176);       //    51,200 B
  int*   gcnt  = (int*)(ws + 4069376);       //    51,200 B

  hipLaunchKernelGGL(k_pre,    dim3(152),  dim3(256), 0, stream,
                     tour_index, list, goff, gcnt, W1, W2, w1f, w2f, ssum);
  hipLaunchKernelGGL(k_gather, dim3(3200), dim3(256), 0, stream, emb, list, goff, gcnt, tourb);
  hipLaunchKernelGGL(k_mlp,    dim3(4000), dim3(256), 0, stream, tour_index, emb, tourb,
                     w1f, w2f, b1, b2, ssum, ssq, out);
  hipLaunchKernelGGL(k_out,    dim3(8004), dim3(256), 0, stream, emb, ssum, ssq, gamma, beta, out);
}

// Round 14
// 209.716 us; speedup vs baseline: 1.0094x; 1.0019x over previous
//
#include <hip/hip_runtime.h>
#include <stdint.h>

typedef unsigned short u16;
typedef __attribute__((ext_vector_type(8))) short short8;
typedef __attribute__((ext_vector_type(4))) float floatx4;

constexpr int B_ = 64, P_ = 2000, D_ = 128, T_ = 200;

__device__ __forceinline__ u16 f2bf(float f) {
  union { float f; uint32_t u; } v; v.f = f;
  return (u16)((v.u + 0x7fffu + ((v.u >> 16) & 1u)) >> 16);
}

// async global->LDS, 16B per lane (global_load_lds_dwordx4). Dest must be
// wave-uniform-base + lane*16 (m104); our staging is tid-linear so this holds.
__device__ __forceinline__ void g2lds16(const void* g, void* l) {
  __builtin_amdgcn_global_load_lds(
      (const __attribute__((address_space(1))) uint32_t*)g,
      (__attribute__((address_space(3))) uint32_t*)l, 16, 0, 0);
}

// ---- fused prologue: blocks 0..63 counting-sort customer ids by tour (per batch);
// blocks 64..127 zero ssum||ssq (ws poisoned 0xAA); blocks 128..151 pack fp32
// W1 (256x128) / W2 (128x128) into bf16 MFMA B-fragment order.
// frag id = (ks*8 + nt)*64 + lane ; lane holds B[k0+j][nt*16 + (lane&15)], j=0..7,
// k0 = ks*32 + (lane>>4)*8.  W1: 8 ksteps (4096 frags). W2: 4 ksteps (2048 frags).
__global__ __launch_bounds__(256) void k_pre(
    const int* __restrict__ tidx, int* __restrict__ list,
    int* __restrict__ goff, int* __restrict__ gcnt,
    const float* __restrict__ W1, const float* __restrict__ W2,
    u16* __restrict__ w1f, u16* __restrict__ w2f, float* __restrict__ ssum) {
  __shared__ int tix[P_];
  __shared__ int cnt[256], scan[256], cur[256];
  const int bid = blockIdx.x, tid = threadIdx.x;

  if (bid >= 64) {
    if (bid < 128) {            // 64*256 = 16384 = 2*B_*D_ exactly
      ssum[(bid - 64) * 256 + tid] = 0.f;
      return;
    }
    int t = (bid - 128) * 256 + tid;   // 24 blocks * 256 = 6144 exactly
    if (t >= 6144) return;
    const float* W = (t < 4096) ? W1 : W2;
    u16* dst = (t < 4096) ? w1f : w2f;
    int fid = (t < 4096) ? t : t - 4096;
    int lane = fid & 63;
    int nt = (fid >> 6) & 7;
    int ks = fid >> 9;
    int quad = lane >> 4, c = lane & 15;
    int k0 = ks * 32 + quad * 8;
#pragma unroll
    for (int j = 0; j < 8; ++j)
      dst[(size_t)fid * 8 + j] = f2bf(W[(k0 + j) * D_ + nt * 16 + c]);
    return;
  }

  // ---- counting sort (one block per batch b = bid). INT LDS atomics only. ----
  const int b = bid;
  cnt[tid] = 0;
  for (int i = tid; i < P_; i += 256) tix[i] = tidx[b * P_ + i];
  __syncthreads();
  for (int i = tid; i < P_; i += 256) atomicAdd(&cnt[tix[i]], 1);
  __syncthreads();
  scan[tid] = cnt[tid];
  __syncthreads();
  for (int s = 1; s < 256; s <<= 1) {
    int v = (tid >= s) ? scan[tid - s] : 0;
    __syncthreads();
    scan[tid] += v;
    __syncthreads();
  }
  int excl = scan[tid] - cnt[tid];
  if (tid < T_) {
    goff[b * T_ + tid] = excl;
    gcnt[b * T_ + tid] = cnt[tid];
  }
  cur[tid] = excl;
  __syncthreads();
  for (int i = tid; i < P_; i += 256) {
    int slot = atomicAdd(&cur[tix[i]], 1);
    list[b * P_ + slot] = i;
  }
}

// ---- gather: one wave per (b,t) segment; register-sum its rows; bf16 write ----
// grid 3200 x 256 thr (4 waves): seg = blockIdx*4 + wave, 12,800 segments exact.
__global__ __launch_bounds__(256) void k_gather(const float* __restrict__ emb,
                                                const int* __restrict__ list,
                                                const int* __restrict__ goff,
                                                const int* __restrict__ gcnt,
                                                u16* __restrict__ tourb) {
  const int tid = threadIdx.x;
  const int lane = tid & 63, wv = tid >> 6;
  const int seg = blockIdx.x * 4 + wv;          // = b*T_ + t
  const int b = seg / T_;
  const int off = goff[seg], cn = gcnt[seg];
  const int* lstb = list + b * P_;
  const float* eb = emb + ((size_t)(b * 2001 + 1)) * D_ + lane * 2;
  float sx = 0.f, sy = 0.f;
  for (int i = 0; i < cn; i += 8) {
    int pr[8];
#pragma unroll
    for (int j = 0; j < 8; ++j)
      if (i + j < cn) pr[j] = lstb[off + i + j];
    float2 v[8];
#pragma unroll
    for (int j = 0; j < 8; ++j)
      if (i + j < cn) v[j] = *(const float2*)(eb + (size_t)pr[j] * D_);
#pragma unroll
    for (int j = 0; j < 8; ++j)
      if (i + j < cn) { sx += v[j].x; sy += v[j].y; }
  }
  uint32_t pk = (uint32_t)f2bf(sx) | ((uint32_t)f2bf(sy) << 16);
  ((uint32_t*)(tourb + (size_t)seg * D_))[lane] = pk;
}

// ---- fused MLP + stats: h = relu(x@W1+b1); h = h@W2+b2; out = cust + h;
// per-(b,col) sum / sumsq accumulated in-kernel.
// FROZEN (R12): six structural variants (R2 82, R5 78, R6 68.5, R8 80, R11 70us)
// bracket a ~68-70us basin — ILP<->TLP, staged<->VMEM weights, barriers 13/10/2,
// tile 32/64 all converge. R11 form kept (equal-best measured, 69.9us).
__global__ __launch_bounds__(256, 5) void k_mlp(
    const int* __restrict__ tidx, const float* __restrict__ emb,
    const u16* __restrict__ tourb,
    const u16* __restrict__ w1f, const u16* __restrict__ w2f,
    const float* __restrict__ b1, const float* __restrict__ b2,
    float* __restrict__ ssum, float* __restrict__ ssq,
    float* __restrict__ out) {
  __shared__ u16 wbuf[2][4096];    // 2 x 8 KB W1 double-buffer (one kstep each)
  __shared__ u16 hbuf[32 * 136];   // stride 136: 16B-aligned rows, 2-way banks (free)
  __shared__ float red[2][2][128]; // [b-slot][sum|sq][col], 2 KB
  const int tid = threadIdx.x;
  const int w = tid >> 6, lane = tid & 63, quad = lane >> 4, c = lane & 15;
  const int wr = w >> 1, wc = w & 1;   // wave's (row, col) position in 2x2 grid
  const int base = blockIdx.x * 32;
  const int r0 = wr * 16;              // wave's 16-row tile within the block

  // zero stats reduction buffer (ordered before epilogue-2 by the mid barriers)
  for (int i = tid; i < 512; i += 256) ((float*)red)[i] = 0.f;

  const int blo = base / P_;
  const int bhi = (base + 31) / P_;
  const bool straddle = (blo != bhi);
  const int bsplit = bhi * P_;

  const int m0 = base + r0 + c;              // this lane's A-row (global row id)
  const int ab = m0 / P_, ap = m0 - ab * P_;
  const float* arow = emb + ((size_t)(ab * 2001 + 1 + ap)) * D_;
  const u16* trow = tourb + ((size_t)(ab * T_ + tidx[m0])) * D_;

  // stage W1 kstep 0 into wbuf[0]: 8 KB = 256 thr x 2 x 16 B, tid-linear.
  g2lds16(w1f + (size_t)tid * 8,        (u16*)wbuf[0] + (size_t)tid * 8);
  g2lds16(w1f + 2048 + (size_t)tid * 8, (u16*)wbuf[0] + 2048 + (size_t)tid * 8);

  // hoist ALL A inputs: 4 fp32 ksteps (32 regs) + 4 bf16 tour ksteps (16 regs).
  floatx4 xa[4][2];
#pragma unroll
  for (int ks = 0; ks < 4; ++ks) {
    const float* src = arow + ks * 32 + quad * 8;
    xa[ks][0] = *(const floatx4*)src;
    xa[ks][1] = *(const floatx4*)(src + 4);
  }
  short8 ta[4];
#pragma unroll
  for (int ks = 0; ks < 4; ++ks)
    ta[ks] = *(const short8*)(trow + ks * 32 + quad * 8);

  float bias1[4], bias2[4];
#pragma unroll
  for (int ntl = 0; ntl < 4; ++ntl) {
    bias1[ntl] = b1[(wc * 4 + ntl) * 16 + c];
    bias2[ntl] = b2[(wc * 4 + ntl) * 16 + c];
  }

  floatx4 acc[4];
#pragma unroll
  for (int ntl = 0; ntl < 4; ++ntl) acc[ntl] = (floatx4)0.f;

  __syncthreads();   // wbuf[0] staged (vmcnt drain) + red zero ordered

  // ---- GEMM1: K=256, 8 ksteps. Per iter: stage next kstep -> compute cur ->
  // barrier (HIP __syncthreads drains vmcnt -> staged buf ready, race-free).
  // ks=7 stages nothing; its barrier only publishes hbuf (drain-free). ----
#pragma unroll
  for (int ks = 0; ks < 8; ++ks) {
    const int cur = ks & 1;
    if (ks < 7) {   // stage W1 kstep ks+1
      const u16* src = w1f + (size_t)(ks + 1) * 4096;
      g2lds16(src + (size_t)tid * 8,        (u16*)wbuf[cur ^ 1] + (size_t)tid * 8);
      g2lds16(src + 2048 + (size_t)tid * 8, (u16*)wbuf[cur ^ 1] + 2048 + (size_t)tid * 8);
    }
    short8 a;
    if (ks < 4) {
#pragma unroll
      for (int j = 0; j < 4; ++j) {
        a[j]     = (short)f2bf(xa[ks][0][j]);
        a[4 + j] = (short)f2bf(xa[ks][1][j]);
      }
    } else {
      a = ta[ks - 4];
    }
#pragma unroll
    for (int ntl = 0; ntl < 4; ++ntl) {
      short8 bf = *(const short8*)(&wbuf[cur][((wc * 4 + ntl) * 64 + lane) * 8]);
      acc[ntl] = __builtin_amdgcn_mfma_f32_16x16x32_bf16(a, bf, acc[ntl], 0, 0, 0);
    }
    if (ks == 7) {
      // epilogue 1 before the barrier: relu(acc+b1) -> hbuf bf16
#pragma unroll
      for (int ntl = 0; ntl < 4; ++ntl)
#pragma unroll
        for (int r = 0; r < 4; ++r) {
          int row = r0 + quad * 4 + r;
          float v = acc[ntl][r] + bias1[ntl];
          hbuf[row * 136 + wc * 64 + ntl * 16 + c] = f2bf(v > 0.f ? v : 0.f);
        }
    }
    __syncthreads();
  }

  // hoist epilogue-2 emb loads: in flight across GEMM2 (barrier-free region).
  float eemb[4][4];
#pragma unroll
  for (int ntl = 0; ntl < 4; ++ntl)
#pragma unroll
    for (int r = 0; r < 4; ++r) {
      int m = base + r0 + quad * 4 + r;
      int b = m / P_, p = m - b * P_;
      eemb[ntl][r] = emb[((size_t)(b * 2001 + 1 + p)) * D_ + wc * 64 + ntl * 16 + c];
    }

  // ---- GEMM2: K=128, 4 ksteps; A-frags from hbuf, W2 frags via VMEM (L2-hot).
  // No barriers: compiler free to pipeline loads across MFMAs. ----
  floatx4 acc2[4];
#pragma unroll
  for (int ntl = 0; ntl < 4; ++ntl) acc2[ntl] = (floatx4)0.f;

#pragma unroll
  for (int ks = 0; ks < 4; ++ks) {
    short8 a = *(const short8*)(&hbuf[(r0 + c) * 136 + ks * 32 + quad * 8]);
#pragma unroll
    for (int ntl = 0; ntl < 4; ++ntl) {
      int nt = wc * 4 + ntl;
      short8 bf = *(const short8*)(w2f + ((size_t)((ks * 8 + nt) * 64 + lane)) * 8);
      acc2[ntl] = __builtin_amdgcn_mfma_f32_16x16x32_bf16(a, bf, acc2[ntl], 0, 0, 0);
    }
  }

  // epilogue 2: out = cust + (acc2 + b2), fused per-column stats.
  float s[4], q[4];
#pragma unroll
  for (int ntl = 0; ntl < 4; ++ntl) { s[ntl] = 0.f; q[ntl] = 0.f; }
#pragma unroll
  for (int ntl = 0; ntl < 4; ++ntl)
#pragma unroll
    for (int r = 0; r < 4; ++r) {
      int row = r0 + quad * 4 + r;
      int m = base + row;
      int b = m / P_, p = m - b * P_;
      int col = wc * 64 + ntl * 16 + c;
      size_t gaddr = ((size_t)(b * 2001 + 1 + p)) * D_ + col;
      float v = eemb[ntl][r] + (acc2[ntl][r] + bias2[ntl]);
      out[gaddr] = v;
      if (!straddle || m < bsplit) {
        s[ntl] += v; q[ntl] += v * v;
      } else {  // rare: block straddles a batch boundary (~32/4000 blocks)
        atomicAdd(&red[1][0][col], v);
        atomicAdd(&red[1][1][col], v * v);
      }
    }
  // fold the quad dimension in-register first (lanes ^16/^32 share col):
#pragma unroll
  for (int ntl = 0; ntl < 4; ++ntl) {
    s[ntl] += __shfl_xor(s[ntl], 16);
    s[ntl] += __shfl_xor(s[ntl], 32);
    q[ntl] += __shfl_xor(q[ntl], 16);
    q[ntl] += __shfl_xor(q[ntl], 32);
  }
  if (quad == 0) {
#pragma unroll
    for (int ntl = 0; ntl < 4; ++ntl) {
      int col = wc * 64 + ntl * 16 + c;
      atomicAdd(&red[0][0][col], s[ntl]);
      atomicAdd(&red[0][1][col], q[ntl]);
    }
  }
  __syncthreads();
  if (tid < 128) {
    atomicAdd(&ssum[blo * D_ + tid], red[0][0][tid]);
    if (straddle) atomicAdd(&ssum[bhi * D_ + tid], red[1][0][tid]);
  } else {
    int col = tid - 128;
    atomicAdd(&ssq[blo * D_ + col], red[0][1][col]);
    if (straddle) atomicAdd(&ssq[bhi * D_ + col], red[1][1][col]);
  }
}

// ---- in-place normalize (rstd/scale recomputed from ssum/ssq per thread)
// + depot-row copy. R12: grid-stride, 2048 blocks (G11 memory-bound sweet spot:
// 8004 tiny blocks -> 2048 blocks x ~3.9 iters; amortizes launch ramp + index
// math, deeper per-wave load/store pipelining).
// R13: resubmitted unchanged (R12 bench never ran: GPU acquisition timeout).
__global__ __launch_bounds__(256) void k_out(
    const float* __restrict__ emb,
    const float* __restrict__ ssum, const float* __restrict__ ssq,
    const float* __restrict__ gamma, const float* __restrict__ beta,
    float* __restrict__ out) {
  constexpr size_t NU = (size_t)B_ * 2001 * D_ / 8;  // 8-float units, exact
  const size_t stride = (size_t)gridDim.x * 256;
  for (size_t u = (size_t)blockIdx.x * 256 + threadIdx.x; u < NU; u += stride) {
    size_t i = u * 8;
    int row = (int)(i >> 7), col = (int)(i & 127);
    int b = row / 2001, r = row - b * 2001;
    if (r == 0) {
      *(floatx4*)(out + i)     = *(const floatx4*)(emb + i);
      *(floatx4*)(out + i + 4) = *(const floatx4*)(emb + i + 4);
    } else {
      floatx4 a0 = *(const floatx4*)(out + i);
      floatx4 a1 = *(const floatx4*)(out + i + 4);
      int cc = b * D_ + col;
      floatx4 su0 = *(const floatx4*)(ssum + cc);
      floatx4 su1 = *(const floatx4*)(ssum + cc + 4);
      floatx4 sq0 = *(const floatx4*)(ssq + cc);
      floatx4 sq1 = *(const floatx4*)(ssq + cc + 4);
      floatx4 g0  = *(const floatx4*)(gamma + col);
      floatx4 g1  = *(const floatx4*)(gamma + col + 4);
      floatx4 be0 = *(const floatx4*)(beta + col);
      floatx4 be1 = *(const floatx4*)(beta + col + 4);
      constexpr float invP = 1.f / P_;
#pragma unroll
      for (int j = 0; j < 4; ++j) {
        float mean = su0[j] * invP;
        float var  = sq0[j] * invP - mean * mean;
        float sc   = rsqrtf(var + 1e-5f) * g0[j];
        a0[j] = a0[j] * sc + (be0[j] - mean * sc);
        float mean1 = su1[j] * invP;
        float var1  = sq1[j] * invP - mean1 * mean1;
        float sc1   = rsqrtf(var1 + 1e-5f) * g1[j];
        a1[j] = a1[j] * sc1 + (be1[j] - mean1 * sc1);
      }
      *(floatx4*)(out + i)     = a0;
      *(floatx4*)(out + i + 4) = a1;
    }
  }
}

extern "C" void kernel_launch(void* const* d_in, const int* in_sizes, int n_in,
                              void* d_out, int out_size, void* d_ws, size_t ws_size,
                              hipStream_t stream) {
  // inputs: 0 batch_size(i32), 1 num_customers(i32), 2 tour_index(i32),
  // 3 embeddings(f32), 4 W1(f32), 5 b1(f32), 6 W2(f32), 7 b2(f32),
  // 8 gamma(f32), 9 beta(f32)
  const int*   tour_index = (const int*)d_in[2];
  const float* emb   = (const float*)d_in[3];
  const float* W1    = (const float*)d_in[4];
  const float* b1    = (const float*)d_in[5];
  const float* W2    = (const float*)d_in[6];
  const float* b2    = (const float*)d_in[7];
  const float* gamma = (const float*)d_in[8];
  const float* beta  = (const float*)d_in[9];
  float* out = (float*)d_out;
  char* ws = (char*)d_ws;

  // ws layout (~4.2 MB):
  u16*   w1f   = (u16*)(ws);                 //    65,536 B
  u16*   w2f   = (u16*)(ws + 65536);         //    32,768 B
  float* ssum  = (float*)(ws + 98304);       //    65,536 B (ssum || ssq)
  float* ssq   = ssum + B_ * D_;
  u16*   tourb = (u16*)(ws + 229376);        // 3,276,800 B (bf16 tour table)
  int*   list  = (int*)(ws + 3506176);       //   512,000 B (sorted customer ids)
  int*   goff  = (int*)(ws + 4018176);       //    51,200 B
  int*   gcnt  = (int*)(ws + 4069376);       //    51,200 B

  hipLaunchKernelGGL(k_pre,    dim3(152),  dim3(256), 0, stream,
                     tour_index, list, goff, gcnt, W1, W2, w1f, w2f, ssum);
  hipLaunchKernelGGL(k_gather, dim3(3200), dim3(256), 0, stream, emb, list, goff, gcnt, tourb);
  hipLaunchKernelGGL(k_mlp,    dim3(4000), dim3(256), 0, stream, tour_index, emb, tourb,
                     w1f, w2f, b1, b2, ssum, ssq, out);
  hipLaunchKernelGGL(k_out,    dim3(2048), dim3(256), 0, stream, emb, ssum, ssq, gamma, beta, out);
}